// Round 8
// baseline (865.576 us; speedup 1.0000x reference)
//
#include <hip/hip_runtime.h>

#define N_NODES 100000
#define N_EDGES 1600000
#define NB 782       // ceil(N_NODES/128) buckets of 128 dst nodes
#define SC_BLK 256   // blocks in the binning passes (blockHist is [NB][SC_BLK])

typedef __attribute__((ext_vector_type(8))) short short8;
typedef __attribute__((ext_vector_type(4))) float float4e;

// async 16B global->LDS copy (lane-contiguous LDS dest)
#define GLDS16(g, l)                                                   \
  __builtin_amdgcn_global_load_lds(                                    \
      (const __attribute__((address_space(1))) unsigned int*)(g),      \
      (__attribute__((address_space(3))) unsigned int*)(l), 16, 0, 0)

// ---------------------------------------------------------------------------
// bf16 split helpers (RNE)
// ---------------------------------------------------------------------------
__device__ __forceinline__ unsigned short f2bf(float f) {
  unsigned u = __float_as_uint(f);
  u += 0x7FFFu + ((u >> 16) & 1u);
  return (unsigned short)(u >> 16);
}
__device__ __forceinline__ float bf2f(unsigned short h) {
  return __uint_as_float(((unsigned)h) << 16);
}

// ===========================================================================
// CSR build, zero global atomics (scratch in d_out, dead before final GEMM).
// ===========================================================================
__global__ __launch_bounds__(256) void histA_k(const int* __restrict__ dst,
                                               int* __restrict__ bh, int nE) {
  __shared__ int h[NB];
  const int blk = blockIdx.x, tid = threadIdx.x;
  for (int b = tid; b < NB; b += 256) h[b] = 0;
  __syncthreads();
  const int epb = (nE + SC_BLK - 1) / SC_BLK;
  const int i1 = min(blk * epb + epb, nE);
  for (int i = blk * epb + tid; i < i1; i += 256)
    atomicAdd(&h[dst[i] >> 7], 1);
  __syncthreads();
  for (int b = tid; b < NB; b += 256) bh[b * SC_BLK + blk] = h[b];
}

// one wave per bucket: exclusive scan of 256 block counts (4/lane + shfl_up)
__global__ __launch_bounds__(256) void scanW_k(int* __restrict__ bh,
                                               int* __restrict__ tot) {
  const int b = blockIdx.x * 4 + (threadIdx.x >> 6);
  const int lane = threadIdx.x & 63;
  if (b >= NB) return;
  const int base = b * SC_BLK + lane * 4;
  int v[4];
#pragma unroll
  for (int j = 0; j < 4; ++j) v[j] = bh[base + j];
  int ls = v[0] + v[1] + v[2] + v[3];
  int x = ls;
  for (int off = 1; off < 64; off <<= 1) {
    int y = __shfl_up(x, off);
    if (lane >= off) x += y;
  }
  int run = x - ls;
#pragma unroll
  for (int j = 0; j < 4; ++j) {
    int t = v[j];
    bh[base + j] = run;
    run += t;
  }
  if (lane == 63) tot[b] = run;
}

__global__ __launch_bounds__(1024) void scanB2_k(const int* __restrict__ tot,
                                                 int* __restrict__ bucketStart) {
  __shared__ int sm[1024];
  const int tid = threadIdx.x;
  int v = (tid < NB) ? tot[tid] : 0;
  sm[tid] = v;
  __syncthreads();
  for (int off = 1; off < 1024; off <<= 1) {
    int t = (tid >= off) ? sm[tid - off] : 0;
    __syncthreads();
    sm[tid] += t;
    __syncthreads();
  }
  if (tid < NB) bucketStart[tid] = sm[tid] - v;
  if (tid == NB - 1) bucketStart[NB] = sm[tid];
}

__global__ __launch_bounds__(256) void scatter2_k(
    const int* __restrict__ src, const int* __restrict__ dst,
    const int* __restrict__ bucketStart, const int* __restrict__ bh,
    unsigned int* __restrict__ packed, int nE) {
  __shared__ int cur[NB];
  const int blk = blockIdx.x, tid = threadIdx.x;
  for (int b = tid; b < NB; b += 256)
    cur[b] = bucketStart[b] + bh[b * SC_BLK + blk];
  __syncthreads();
  const int epb = (nE + SC_BLK - 1) / SC_BLK;
  const int i1 = min(blk * epb + epb, nE);
  for (int i = blk * epb + tid; i < i1; i += 256) {
    int d = dst[i];
    int s = src[i];
    int p = atomicAdd(&cur[d >> 7], 1);  // LDS atomic only
    packed[p] = ((unsigned)s << 7) | (unsigned)(d & 127);
  }
}

// one block per bucket: LDS node-count + local scan -> rowEnd; LDS-cursor
// scatter of sortedSrc confined to this bucket's contiguous CSR range.
__global__ __launch_bounds__(256) void fillB_k(
    const int* __restrict__ bucketStart, const unsigned int* __restrict__ packed,
    int* __restrict__ rowEnd, int* __restrict__ sortedSrc, int nNodes) {
  __shared__ int cnt[128];
  __shared__ int cur[128];
  const int b = blockIdx.x;
  const int tid = threadIdx.x;
  const int s0 = bucketStart[b];
  const int ne = bucketStart[b + 1] - s0;
  if (tid < 128) cnt[tid] = 0;
  __syncthreads();
  for (int i = tid; i < ne; i += 256)
    atomicAdd(&cnt[packed[s0 + i] & 127u], 1);
  __syncthreads();
  int v = (tid < 128) ? cnt[tid] : 0;
  for (int off = 1; off < 128; off <<= 1) {
    int t = (tid < 128 && tid >= off) ? cnt[tid - off] : 0;
    __syncthreads();
    if (tid < 128) cnt[tid] += t;
    __syncthreads();
  }
  if (tid < 128) {
    cur[tid] = s0 + cnt[tid] - v;
    int node = b * 128 + tid;
    if (node < nNodes) rowEnd[node] = s0 + cnt[tid];
  }
  __syncthreads();
  for (int i = tid; i < ne; i += 256) {
    unsigned p = packed[s0 + i];
    int idx = atomicAdd(&cur[p & 127u], 1);
    sortedSrc[idx] = (int)(p >> 7);
  }
}

// ===========================================================================
// Weight prep: W[K][N] fp32 -> transposed bf16 hi/lo planes [N][K].
// ===========================================================================
__global__ __launch_bounds__(256) void wprep_k(
    const float* __restrict__ W, unsigned short* __restrict__ th,
    unsigned short* __restrict__ tl, int K, int N) {
  int i = blockIdx.x * blockDim.x + threadIdx.x;
  if (i < K * N) {
    int k = i / N, n = i % N;
    float v = W[i];
    unsigned short h = f2bf(v);
    unsigned short l = f2bf(v - bf2f(h));
    th[(long)n * K + k] = h;
    tl[(long)n * K + k] = l;
  }
}

// x fp32 -> bf16 hi plane (for the gather path)
__global__ __launch_bounds__(256) void xprep_k(const float* __restrict__ x,
                                               unsigned short* __restrict__ xh,
                                               int n) {
  int i = blockIdx.x * blockDim.x + threadIdx.x;
  if (i < n) xh[i] = f2bf(x[i]);
}

// ===========================================================================
// CSR gather-sum (bf16 rows) + GIN combine -> bf16 hi/lo planes.
//   Processes a 128-channel slice [off, off+128) of rows with stride S.
// One wave per node; lane holds 2 channels; 8-deep gather window.
// ===========================================================================
template <bool XF32>
__global__ __launch_bounds__(256) void agg_s_k(
    const unsigned short* __restrict__ feat_h, const float* __restrict__ xf,
    const unsigned short* __restrict__ xh, const unsigned short* __restrict__ xl,
    const float* __restrict__ epsp, const int* __restrict__ rowEnd,
    const int* __restrict__ sortedSrc, unsigned short* __restrict__ oh,
    unsigned short* __restrict__ ol, int M, int S, int off) {
  constexpr int V = 2;
  const int lane = threadIdx.x & 63;
  const int w = (int)((blockIdx.x * blockDim.x + threadIdx.x) >> 6);
  if (w >= M) return;
  const int start = w ? rowEnd[w - 1] : 0;
  const int end = rowEnd[w];
  const int c0 = lane * V + off;

  float acc[V] = {};
  int e = start;
  for (; e + 8 <= end; e += 8) {
    int si[8];
#pragma unroll
    for (int q = 0; q < 8; ++q) si[q] = sortedSrc[e + q];
    ushort2 t[8];
#pragma unroll
    for (int q = 0; q < 8; ++q)
      t[q] = *(const ushort2*)(feat_h + (long)si[q] * S + c0);
#pragma unroll
    for (int q = 0; q < 8; ++q) {
      acc[0] += bf2f(t[q].x);
      acc[1] += bf2f(t[q].y);
    }
  }
  for (; e + 4 <= end; e += 4) {
    int s0 = sortedSrc[e + 0];
    int s1 = sortedSrc[e + 1];
    int s2 = sortedSrc[e + 2];
    int s3 = sortedSrc[e + 3];
    ushort2 a = *(const ushort2*)(feat_h + (long)s0 * S + c0);
    ushort2 b = *(const ushort2*)(feat_h + (long)s1 * S + c0);
    ushort2 c = *(const ushort2*)(feat_h + (long)s2 * S + c0);
    ushort2 d = *(const ushort2*)(feat_h + (long)s3 * S + c0);
    acc[0] += bf2f(a.x) + bf2f(b.x) + bf2f(c.x) + bf2f(d.x);
    acc[1] += bf2f(a.y) + bf2f(b.y) + bf2f(c.y) + bf2f(d.y);
  }
  for (; e < end; ++e) {
    ushort2 a = *(const ushort2*)(feat_h + (long)sortedSrc[e] * S + c0);
    acc[0] += bf2f(a.x);
    acc[1] += bf2f(a.y);
  }

  const float s = 1.0f + epsp[0];
  float xv[V];
  if constexpr (XF32) {
#pragma unroll
    for (int v = 0; v < V; ++v) xv[v] = xf[(long)w * S + c0 + v];
  } else {
#pragma unroll
    for (int v = 0; v < V; ++v)
      xv[v] = bf2f(xh[(long)w * S + c0 + v]) + bf2f(xl[(long)w * S + c0 + v]);
  }

  unsigned short hv[V], lv[V];
#pragma unroll
  for (int v = 0; v < V; ++v) {
    float res = fmaf(s, xv[v], acc[v]);
    hv[v] = f2bf(res);
    lv[v] = f2bf(res - bf2f(hv[v]));
  }
  *(ushort2*)&oh[(long)w * S + c0] = make_ushort2(hv[0], hv[1]);
  *(ushort2*)&ol[(long)w * S + c0] = make_ushort2(lv[0], lv[1]);
}

// ===========================================================================
// FUSED MLP pair: out = act2(relu(A @ B1 + b1) @ B2 + b2), one kernel.
//   Block = 128 rows x full width. 4 waves (2x2). Mid dim fixed 256 = K2.
//   Phase 1: A (hilo, [M][K1]) staged via proven XOR-swizzled LDS (R6) +
//            B1 frags read DIRECTLY from L2 (weights tiny) -> acc1[4][8].
//   T-tile:  relu(acc1+b1) split to bf16 hilo -> LDS, 8 swizzled [128][32]
//            subtiles (same geometry as the A-tile = proven conflict-free;
//            we control write AND read, so swizzle is consistent).
//   Phase 2: A-frags from LDS T (no staging, NO barriers) x B2 from L2 ->
//            acc2 -> bias2 (+relu) -> store (hilo or f32).
//   Eliminates the T1/T2 HBM round-trips (205 MB each pair).
//   LDS: 16KB A + 128KB T = 144KB -> 1 block/CU; launch_bounds(256,1)
//   gives regalloc 512 VGPRs (acc1 dies before acc2 lives).
// ===========================================================================
__device__ __forceinline__ short8 lds_rd(const unsigned short* base, int r,
                                         int q) {
  int L = r * 64 + q * 16;
  int P = L ^ (((L >> 7) & 7) << 4);
  return *(const short8*)((const char*)base + P);
}

#define MFMA_BF16 __builtin_amdgcn_mfma_f32_16x16x32_bf16

template <int K1, int NF2, bool RELU2, bool HILO2>
__global__ __launch_bounds__(256, 1) void gemm_fused_k(
    const unsigned short* __restrict__ Ah, const unsigned short* __restrict__ Al,
    const unsigned short* __restrict__ B1th, const unsigned short* __restrict__ B1tl,
    const float* __restrict__ bias1,
    const unsigned short* __restrict__ B2th, const unsigned short* __restrict__ B2tl,
    const float* __restrict__ bias2,
    float* __restrict__ outf, unsigned short* __restrict__ oh,
    unsigned short* __restrict__ ol, int M) {
  constexpr int N2 = NF2 * 32;
  __shared__ unsigned short Ash[128 * 32];      // 8 KB
  __shared__ unsigned short Asl[128 * 32];      // 8 KB
  __shared__ unsigned short Th[8 * 128 * 32];   // 64 KB (8 k-subtiles)
  __shared__ unsigned short Tl[8 * 128 * 32];   // 64 KB

  const int tid = threadIdx.x;
  const int lane = tid & 63;
  const int wave = tid >> 6;
  const int l15 = lane & 15;
  const int quad = lane >> 4;
  const int wm = wave >> 1;
  const int wn = wave & 1;
  const int m0 = blockIdx.x * 128;

  // ---------------- phase 1: T = relu(A @ B1 + bias1) -> LDS ----------------
  {
    float4e acc1[4][8];
#pragma unroll
    for (int i = 0; i < 4; ++i)
#pragma unroll
      for (int j = 0; j < 8; ++j) acc1[i][j] = 0.0f;

    for (int k0 = 0; k0 < K1; k0 += 32) {
#pragma unroll
      for (int h = 0; h < 2; ++h) {
        int c = h * 256 + tid;                  // physical 16B chunk
        int P = c * 16;
        int L = P ^ (((P >> 7) & 7) << 4);      // involutive swizzle
        int r = L >> 6;
        int q = (L >> 4) & 3;
        int ra = min(m0 + r, M - 1);            // clamp: masked rows only
        long ga = (long)ra * K1 + k0 + q * 8;
        GLDS16(Ah + ga, &Ash[c * 8]);
        GLDS16(Al + ga, &Asl[c * 8]);
      }
      __syncthreads();

      short8 ah[4], al[4];
#pragma unroll
      for (int mi = 0; mi < 4; ++mi) {
        ah[mi] = lds_rd(Ash, wm * 64 + mi * 16 + l15, quad);
        al[mi] = lds_rd(Asl, wm * 64 + mi * 16 + l15, quad);
      }
#pragma unroll
      for (int ni = 0; ni < 8; ++ni) {
        int n = wn * 128 + ni * 16 + l15;
        short8 bh = *(const short8*)(B1th + (long)n * K1 + k0 + quad * 8);
        short8 bl = *(const short8*)(B1tl + (long)n * K1 + k0 + quad * 8);
#pragma unroll
        for (int mi = 0; mi < 4; ++mi) {
          acc1[mi][ni] = MFMA_BF16(ah[mi], bh, acc1[mi][ni], 0, 0, 0);
          acc1[mi][ni] = MFMA_BF16(ah[mi], bl, acc1[mi][ni], 0, 0, 0);
          acc1[mi][ni] = MFMA_BF16(al[mi], bh, acc1[mi][ni], 0, 0, 0);
        }
      }
      __syncthreads();
    }

    // epilogue 1: relu(acc1+b1) -> hilo bf16 -> swizzled T subtiles
#pragma unroll
    for (int ni = 0; ni < 8; ++ni) {
      int col = wn * 128 + ni * 16 + l15;       // mid index = phase-2 k
      float bj = bias1[col];
      int sb = (col >> 5) * 4096;               // k-subtile base (elems)
      int c5 = (col & 31) * 2;                  // byte offset within row
#pragma unroll
      for (int mi = 0; mi < 4; ++mi) {
#pragma unroll
        for (int r = 0; r < 4; ++r) {
          int row = wm * 64 + mi * 16 + quad * 4 + r;
          float v = fmaxf(acc1[mi][ni][r] + bj, 0.0f);
          unsigned short hv = f2bf(v);
          unsigned short lv = f2bf(v - bf2f(hv));
          int L = row * 64 + c5;
          int P = L ^ (((L >> 7) & 7) << 4);
          *(unsigned short*)((char*)(Th + sb) + P) = hv;
          *(unsigned short*)((char*)(Tl + sb) + P) = lv;
        }
      }
    }
  }
  __syncthreads();

  // ---------------- phase 2: out = act2(T @ B2 + bias2) ---------------------
  float4e acc2[4][NF2];
#pragma unroll
  for (int i = 0; i < 4; ++i)
#pragma unroll
    for (int j = 0; j < NF2; ++j) acc2[i][j] = 0.0f;

  for (int kt = 0; kt < 8; ++kt) {              // K2 = 256, no barriers
    short8 ah2[4], al2[4];
#pragma unroll
    for (int mi = 0; mi < 4; ++mi) {
      ah2[mi] = lds_rd(Th + kt * 4096, wm * 64 + mi * 16 + l15, quad);
      al2[mi] = lds_rd(Tl + kt * 4096, wm * 64 + mi * 16 + l15, quad);
    }
#pragma unroll
    for (int ni = 0; ni < NF2; ++ni) {
      int n = wn * (NF2 * 16) + ni * 16 + l15;
      short8 bh = *(const short8*)(B2th + (long)n * 256 + kt * 32 + quad * 8);
      short8 bl = *(const short8*)(B2tl + (long)n * 256 + kt * 32 + quad * 8);
#pragma unroll
      for (int mi = 0; mi < 4; ++mi) {
        acc2[mi][ni] = MFMA_BF16(ah2[mi], bh, acc2[mi][ni], 0, 0, 0);
        acc2[mi][ni] = MFMA_BF16(ah2[mi], bl, acc2[mi][ni], 0, 0, 0);
        acc2[mi][ni] = MFMA_BF16(al2[mi], bh, acc2[mi][ni], 0, 0, 0);
      }
    }
  }

#pragma unroll
  for (int ni = 0; ni < NF2; ++ni) {
    int col = wn * (NF2 * 16) + ni * 16 + l15;
    float bj = bias2[col];
#pragma unroll
    for (int mi = 0; mi < 4; ++mi) {
#pragma unroll
      for (int r = 0; r < 4; ++r) {
        int row = m0 + wm * 64 + mi * 16 + quad * 4 + r;
        if (row < M) {
          float v = acc2[mi][ni][r] + bj;
          if constexpr (RELU2) v = fmaxf(v, 0.0f);
          if constexpr (HILO2) {
            unsigned short hv = f2bf(v);
            oh[(long)row * N2 + col] = hv;
            ol[(long)row * N2 + col] = f2bf(v - bf2f(hv));
          } else {
            outf[(long)row * N2 + col] = v;
          }
        }
      }
    }
  }
}

extern "C" void kernel_launch(void* const* d_in, const int* in_sizes, int n_in,
                              void* d_out, int out_size, void* d_ws, size_t ws_size,
                              hipStream_t stream) {
  const float* x    = (const float*)d_in[0];
  const int*   ei   = (const int*)d_in[1];
  const float* eps1 = (const float*)d_in[2];
  const float* W1a  = (const float*)d_in[3];
  const float* b1a  = (const float*)d_in[4];
  const float* W1b  = (const float*)d_in[5];
  const float* b1b  = (const float*)d_in[6];
  const float* eps2 = (const float*)d_in[7];
  const float* W2a  = (const float*)d_in[8];
  const float* b2a  = (const float*)d_in[9];
  const float* W2b  = (const float*)d_in[10];
  const float* b2b  = (const float*)d_in[11];
  float* out = (float*)d_out;

  const int* srcp = ei;
  const int* dstp = ei + N_EDGES;

  // ---- workspace: two 102.4MB halves ----
  // P1: phase A = C1 hilo [M][128] + xh; phase C = C2 hilo [M][256]
  // P2: phase B = H hilo [M][256];    phase D = W2a/W2b planes (H dead)
  char* ws = (char*)d_ws;
  const size_t SZ = (size_t)N_NODES * 256 * sizeof(float);  // 102.4 MB
  char* P1 = ws;
  char* P2 = ws + SZ;

  unsigned short* C1h = (unsigned short*)P1;
  unsigned short* C1l = C1h + (size_t)N_NODES * 128;
  unsigned short* xh  = C1l + (size_t)N_NODES * 128;
  unsigned short* Hh  = (unsigned short*)P2;
  unsigned short* Hl  = Hh + (size_t)N_NODES * 256;
  unsigned short* C2h = (unsigned short*)P1;
  unsigned short* C2l = C2h + (size_t)N_NODES * 256;
  unsigned short* W2ah = (unsigned short*)P2;   // written AFTER agg2 (H dead)
  unsigned short* W2al = W2ah + 256 * 256;
  unsigned short* W2bh = W2al + 256 * 256;
  unsigned short* W2bl = W2bh + 128 * 256;

  // ---- d_out scratch (CSR + W1 planes; all dead before fused-L2 writes) ----
  char* ob = (char*)d_out;
  int* rowEnd    = (int*)(ob + 400 * 1024);
  int* sortedSrc = (int*)(ob + 800 * 1024);
  size_t wofs = 7340032;
  unsigned short* W1ah = (unsigned short*)(ob + wofs);
  unsigned short* W1al = W1ah + 256 * 128;
  unsigned short* W1bh = (unsigned short*)(ob + wofs + 2 * 65536);
  unsigned short* W1bl = W1bh + 256 * 256;
  unsigned int* packed = (unsigned int*)(ob + 16 * 1024 * 1024);   // 6.4MB
  int* bucketStart = (int*)(ob + 28 * 1024 * 1024);                // NB+1 ints
  int* bucketTot   = (int*)(ob + 28 * 1024 * 1024 + 8192);         // NB ints
  int* blockHist   = (int*)(ob + 30 * 1024 * 1024);                // NB*SC_BLK

  dim3 blk(256);
  dim3 gAgg((N_NODES + 3) / 4);
  dim3 gW1((128 * 256 + 255) / 256);
  dim3 gW2((256 * 256 + 255) / 256);
  dim3 gXp((N_NODES * 128 + 255) / 256);
  dim3 gFused((N_NODES + 127) / 128);  // 782

  // ---- CSR build (no global atomics) + weight/x prep ----
  histA_k<<<dim3(SC_BLK), blk, 0, stream>>>(dstp, blockHist, N_EDGES);
  scanW_k<<<dim3((NB + 3) / 4), blk, 0, stream>>>(blockHist, bucketTot);
  scanB2_k<<<1, dim3(1024), 0, stream>>>(bucketTot, bucketStart);
  scatter2_k<<<dim3(SC_BLK), blk, 0, stream>>>(srcp, dstp, bucketStart,
                                               blockHist, packed, N_EDGES);
  fillB_k<<<dim3(NB), blk, 0, stream>>>(bucketStart, packed, rowEnd, sortedSrc,
                                        N_NODES);
  xprep_k<<<gXp, blk, 0, stream>>>(x, xh, N_NODES * 128);
  wprep_k<<<gW1, blk, 0, stream>>>(W1a, W1ah, W1al, 128, 256);
  wprep_k<<<gW2, blk, 0, stream>>>(W1b, W1bh, W1bl, 256, 256);

  // ---- Layer 1: agg -> fused MLP (C1 -> H, T1 never touches HBM) ----
  agg_s_k<true><<<gAgg, blk, 0, stream>>>(
      xh, x, nullptr, nullptr, eps1, rowEnd, sortedSrc, C1h, C1l, N_NODES, 128, 0);
  gemm_fused_k<128, 8, true, true><<<gFused, blk, 0, stream>>>(
      C1h, C1l, W1ah, W1al, b1a, W1bh, W1bl, b1b, nullptr, Hh, Hl, N_NODES);

  // ---- Layer 2: agg -> W2 prep (H dead) -> fused MLP (C2 -> out) ----
  agg_s_k<false><<<gAgg, blk, 0, stream>>>(
      Hh, nullptr, Hh, Hl, eps2, rowEnd, sortedSrc, C2h, C2l, N_NODES, 256, 0);
  agg_s_k<false><<<gAgg, blk, 0, stream>>>(
      Hh, nullptr, Hh, Hl, eps2, rowEnd, sortedSrc, C2h, C2l, N_NODES, 256, 128);
  wprep_k<<<gW2, blk, 0, stream>>>(W2a, W2ah, W2al, 256, 256);
  wprep_k<<<gW1, blk, 0, stream>>>(W2b, W2bh, W2bl, 256, 128);
  gemm_fused_k<256, 4, false, false><<<gFused, blk, 0, stream>>>(
      C2h, C2l, W2ah, W2al, b2a, W2bh, W2bl, b2b, out, nullptr, nullptr,
      N_NODES);
}

// Round 9
// 833.588 us; speedup vs baseline: 1.0384x; 1.0384x over previous
//
#include <hip/hip_runtime.h>

#define N_NODES 100000
#define N_EDGES 1600000
#define NB 782       // ceil(N_NODES/128) buckets of 128 dst nodes
#define SC_BLK 256   // blocks in the binning passes (blockHist is [NB][SC_BLK])

typedef __attribute__((ext_vector_type(8))) short short8;
typedef __attribute__((ext_vector_type(4))) float float4e;

// async 16B global->LDS copy (lane-contiguous LDS dest)
#define GLDS16(g, l)                                                   \
  __builtin_amdgcn_global_load_lds(                                    \
      (const __attribute__((address_space(1))) unsigned int*)(g),      \
      (__attribute__((address_space(3))) unsigned int*)(l), 16, 0, 0)

// ---------------------------------------------------------------------------
// bf16 split helpers (RNE)
// ---------------------------------------------------------------------------
__device__ __forceinline__ unsigned short f2bf(float f) {
  unsigned u = __float_as_uint(f);
  u += 0x7FFFu + ((u >> 16) & 1u);
  return (unsigned short)(u >> 16);
}
__device__ __forceinline__ float bf2f(unsigned short h) {
  return __uint_as_float(((unsigned)h) << 16);
}

// ===========================================================================
// CSR build, zero global atomics (scratch in d_out, dead before final GEMM).
// ===========================================================================
__global__ __launch_bounds__(256) void histA_k(const int* __restrict__ dst,
                                               int* __restrict__ bh, int nE) {
  __shared__ int h[NB];
  const int blk = blockIdx.x, tid = threadIdx.x;
  for (int b = tid; b < NB; b += 256) h[b] = 0;
  __syncthreads();
  const int epb = (nE + SC_BLK - 1) / SC_BLK;
  const int i1 = min(blk * epb + epb, nE);
  for (int i = blk * epb + tid; i < i1; i += 256)
    atomicAdd(&h[dst[i] >> 7], 1);
  __syncthreads();
  for (int b = tid; b < NB; b += 256) bh[b * SC_BLK + blk] = h[b];
}

// one wave per bucket: exclusive scan of 256 block counts (4/lane + shfl_up)
__global__ __launch_bounds__(256) void scanW_k(int* __restrict__ bh,
                                               int* __restrict__ tot) {
  const int b = blockIdx.x * 4 + (threadIdx.x >> 6);
  const int lane = threadIdx.x & 63;
  if (b >= NB) return;
  const int base = b * SC_BLK + lane * 4;
  int v[4];
#pragma unroll
  for (int j = 0; j < 4; ++j) v[j] = bh[base + j];
  int ls = v[0] + v[1] + v[2] + v[3];
  int x = ls;
  for (int off = 1; off < 64; off <<= 1) {
    int y = __shfl_up(x, off);
    if (lane >= off) x += y;
  }
  int run = x - ls;
#pragma unroll
  for (int j = 0; j < 4; ++j) {
    int t = v[j];
    bh[base + j] = run;
    run += t;
  }
  if (lane == 63) tot[b] = run;
}

__global__ __launch_bounds__(1024) void scanB2_k(const int* __restrict__ tot,
                                                 int* __restrict__ bucketStart) {
  __shared__ int sm[1024];
  const int tid = threadIdx.x;
  int v = (tid < NB) ? tot[tid] : 0;
  sm[tid] = v;
  __syncthreads();
  for (int off = 1; off < 1024; off <<= 1) {
    int t = (tid >= off) ? sm[tid - off] : 0;
    __syncthreads();
    sm[tid] += t;
    __syncthreads();
  }
  if (tid < NB) bucketStart[tid] = sm[tid] - v;
  if (tid == NB - 1) bucketStart[NB] = sm[tid];
}

__global__ __launch_bounds__(256) void scatter2_k(
    const int* __restrict__ src, const int* __restrict__ dst,
    const int* __restrict__ bucketStart, const int* __restrict__ bh,
    unsigned int* __restrict__ packed, int nE) {
  __shared__ int cur[NB];
  const int blk = blockIdx.x, tid = threadIdx.x;
  for (int b = tid; b < NB; b += 256)
    cur[b] = bucketStart[b] + bh[b * SC_BLK + blk];
  __syncthreads();
  const int epb = (nE + SC_BLK - 1) / SC_BLK;
  const int i1 = min(blk * epb + epb, nE);
  for (int i = blk * epb + tid; i < i1; i += 256) {
    int d = dst[i];
    int s = src[i];
    int p = atomicAdd(&cur[d >> 7], 1);  // LDS atomic only
    packed[p] = ((unsigned)s << 7) | (unsigned)(d & 127);
  }
}

// one block per bucket: LDS node-count + local scan -> rowEnd; LDS-cursor
// scatter of sortedSrc confined to this bucket's contiguous CSR range.
__global__ __launch_bounds__(256) void fillB_k(
    const int* __restrict__ bucketStart, const unsigned int* __restrict__ packed,
    int* __restrict__ rowEnd, int* __restrict__ sortedSrc, int nNodes) {
  __shared__ int cnt[128];
  __shared__ int cur[128];
  const int b = blockIdx.x;
  const int tid = threadIdx.x;
  const int s0 = bucketStart[b];
  const int ne = bucketStart[b + 1] - s0;
  if (tid < 128) cnt[tid] = 0;
  __syncthreads();
  for (int i = tid; i < ne; i += 256)
    atomicAdd(&cnt[packed[s0 + i] & 127u], 1);
  __syncthreads();
  int v = (tid < 128) ? cnt[tid] : 0;
  for (int off = 1; off < 128; off <<= 1) {
    int t = (tid < 128 && tid >= off) ? cnt[tid - off] : 0;
    __syncthreads();
    if (tid < 128) cnt[tid] += t;
    __syncthreads();
  }
  if (tid < 128) {
    cur[tid] = s0 + cnt[tid] - v;
    int node = b * 128 + tid;
    if (node < nNodes) rowEnd[node] = s0 + cnt[tid];
  }
  __syncthreads();
  for (int i = tid; i < ne; i += 256) {
    unsigned p = packed[s0 + i];
    int idx = atomicAdd(&cur[p & 127u], 1);
    sortedSrc[idx] = (int)(p >> 7);
  }
}

// ===========================================================================
// Weight prep: W[K][N] fp32 -> transposed bf16 hi/lo planes [N][K].
// ===========================================================================
__global__ __launch_bounds__(256) void wprep_k(
    const float* __restrict__ W, unsigned short* __restrict__ th,
    unsigned short* __restrict__ tl, int K, int N) {
  int i = blockIdx.x * blockDim.x + threadIdx.x;
  if (i < K * N) {
    int k = i / N, n = i % N;
    float v = W[i];
    unsigned short h = f2bf(v);
    unsigned short l = f2bf(v - bf2f(h));
    th[(long)n * K + k] = h;
    tl[(long)n * K + k] = l;
  }
}

// x fp32 -> bf16 hi plane (for the gather path)
__global__ __launch_bounds__(256) void xprep_k(const float* __restrict__ x,
                                               unsigned short* __restrict__ xh,
                                               int n) {
  int i = blockIdx.x * blockDim.x + threadIdx.x;
  if (i < n) xh[i] = f2bf(x[i]);
}

// ===========================================================================
// CSR gather-sum (bf16 rows) + GIN combine -> bf16 hi/lo planes.
//   Processes a 128-channel slice [off, off+128) of rows with stride S.
// One wave per node; lane holds 2 channels; 8-deep gather window.
// ===========================================================================
template <bool XF32>
__global__ __launch_bounds__(256) void agg_s_k(
    const unsigned short* __restrict__ feat_h, const float* __restrict__ xf,
    const unsigned short* __restrict__ xh, const unsigned short* __restrict__ xl,
    const float* __restrict__ epsp, const int* __restrict__ rowEnd,
    const int* __restrict__ sortedSrc, unsigned short* __restrict__ oh,
    unsigned short* __restrict__ ol, int M, int S, int off) {
  constexpr int V = 2;
  const int lane = threadIdx.x & 63;
  const int w = (int)((blockIdx.x * blockDim.x + threadIdx.x) >> 6);
  if (w >= M) return;
  const int start = w ? rowEnd[w - 1] : 0;
  const int end = rowEnd[w];
  const int c0 = lane * V + off;

  float acc[V] = {};
  int e = start;
  for (; e + 8 <= end; e += 8) {
    int si[8];
#pragma unroll
    for (int q = 0; q < 8; ++q) si[q] = sortedSrc[e + q];
    ushort2 t[8];
#pragma unroll
    for (int q = 0; q < 8; ++q)
      t[q] = *(const ushort2*)(feat_h + (long)si[q] * S + c0);
#pragma unroll
    for (int q = 0; q < 8; ++q) {
      acc[0] += bf2f(t[q].x);
      acc[1] += bf2f(t[q].y);
    }
  }
  for (; e + 4 <= end; e += 4) {
    int s0 = sortedSrc[e + 0];
    int s1 = sortedSrc[e + 1];
    int s2 = sortedSrc[e + 2];
    int s3 = sortedSrc[e + 3];
    ushort2 a = *(const ushort2*)(feat_h + (long)s0 * S + c0);
    ushort2 b = *(const ushort2*)(feat_h + (long)s1 * S + c0);
    ushort2 c = *(const ushort2*)(feat_h + (long)s2 * S + c0);
    ushort2 d = *(const ushort2*)(feat_h + (long)s3 * S + c0);
    acc[0] += bf2f(a.x) + bf2f(b.x) + bf2f(c.x) + bf2f(d.x);
    acc[1] += bf2f(a.y) + bf2f(b.y) + bf2f(c.y) + bf2f(d.y);
  }
  for (; e < end; ++e) {
    ushort2 a = *(const ushort2*)(feat_h + (long)sortedSrc[e] * S + c0);
    acc[0] += bf2f(a.x);
    acc[1] += bf2f(a.y);
  }

  const float s = 1.0f + epsp[0];
  float xv[V];
  if constexpr (XF32) {
#pragma unroll
    for (int v = 0; v < V; ++v) xv[v] = xf[(long)w * S + c0 + v];
  } else {
#pragma unroll
    for (int v = 0; v < V; ++v)
      xv[v] = bf2f(xh[(long)w * S + c0 + v]) + bf2f(xl[(long)w * S + c0 + v]);
  }

  unsigned short hv[V], lv[V];
#pragma unroll
  for (int v = 0; v < V; ++v) {
    float res = fmaf(s, xv[v], acc[v]);
    hv[v] = f2bf(res);
    lv[v] = f2bf(res - bf2f(hv[v]));
  }
  *(ushort2*)&oh[(long)w * S + c0] = make_ushort2(hv[0], hv[1]);
  *(ushort2*)&ol[(long)w * S + c0] = make_ushort2(lv[0], lv[1]);
}

// ===========================================================================
// Split-bf16 MFMA GEMM, full-N block: 128 rows x N (N = NF*32), 4 waves
// (2x2), wave = 64 x N/2 = acc[4][NF]. A staged ONCE via XOR-swizzled LDS
// (16 KB, zero conflicts -- R6-proven); B read DIRECTLY from global (weights
// <=256KB hilo, L2-resident after first block). vs R6: A fetched once (no
// grid.y), 4 gload_lds/thread per K-step instead of 8, 2x MFMA per barrier
// window. Single-buffered, plain __syncthreads (R7 showed counted-vmcnt
// dbuf regresses at this occupancy).
// ===========================================================================
__device__ __forceinline__ short8 lds_rd(const unsigned short* base, int r,
                                         int q) {
  int L = r * 64 + q * 16;
  int P = L ^ (((L >> 7) & 7) << 4);
  return *(const short8*)((const char*)base + P);
}

#define MFMA_BF16 __builtin_amdgcn_mfma_f32_16x16x32_bf16

template <int NF, bool RELU, bool HILO>
__global__ __launch_bounds__(256, 2) void gemmW_k(
    const unsigned short* __restrict__ Ah, const unsigned short* __restrict__ Al,
    const unsigned short* __restrict__ Bth, const unsigned short* __restrict__ Btl,
    const float* __restrict__ bias, float* __restrict__ outf,
    unsigned short* __restrict__ oh, unsigned short* __restrict__ ol,
    int M, int K) {
  constexpr int N = NF * 32;
  __shared__ unsigned short Ash[128 * 32];  // 8 KB
  __shared__ unsigned short Asl[128 * 32];  // 8 KB

  const int tid = threadIdx.x;
  const int lane = tid & 63;
  const int wave = tid >> 6;
  const int l15 = lane & 15;
  const int quad = lane >> 4;
  const int wm = wave >> 1;
  const int wn = wave & 1;
  const int m0 = blockIdx.x * 128;

  float4e acc[4][NF];
#pragma unroll
  for (int i = 0; i < 4; ++i)
#pragma unroll
    for (int j = 0; j < NF; ++j) acc[i][j] = 0.0f;

  for (int k0 = 0; k0 < K; k0 += 32) {
    // stage A only: 2 chunks/thread/plane, swizzled source -> linear dest
#pragma unroll
    for (int h = 0; h < 2; ++h) {
      int c = h * 256 + tid;                  // physical 16B chunk
      int P = c * 16;
      int L = P ^ (((P >> 7) & 7) << 4);      // involutive swizzle
      int r = L >> 6;
      int q = (L >> 4) & 3;
      int ra = min(m0 + r, M - 1);            // clamp: masked rows only
      long ga = (long)ra * K + k0 + q * 8;
      GLDS16(Ah + ga, &Ash[c * 8]);
      GLDS16(Al + ga, &Asl[c * 8]);
    }
    __syncthreads();

    short8 ah[4], al[4];
#pragma unroll
    for (int mi = 0; mi < 4; ++mi) {
      ah[mi] = lds_rd(Ash, wm * 64 + mi * 16 + l15, quad);
      al[mi] = lds_rd(Asl, wm * 64 + mi * 16 + l15, quad);
    }
#pragma unroll
    for (int ni = 0; ni < NF; ++ni) {
      int n = wn * (NF * 16) + ni * 16 + l15;
      short8 bh = *(const short8*)(Bth + (long)n * K + k0 + quad * 8);
      short8 bl = *(const short8*)(Btl + (long)n * K + k0 + quad * 8);
#pragma unroll
      for (int mi = 0; mi < 4; ++mi) {
        acc[mi][ni] = MFMA_BF16(ah[mi], bh, acc[mi][ni], 0, 0, 0);
        acc[mi][ni] = MFMA_BF16(ah[mi], bl, acc[mi][ni], 0, 0, 0);
        acc[mi][ni] = MFMA_BF16(al[mi], bh, acc[mi][ni], 0, 0, 0);
      }
    }
    __syncthreads();
  }

#pragma unroll
  for (int ni = 0; ni < NF; ++ni) {
    int col = wn * (NF * 16) + ni * 16 + l15;
    float bj = bias[col];
#pragma unroll
    for (int mi = 0; mi < 4; ++mi) {
      int rbase = m0 + wm * 64 + mi * 16 + quad * 4;
#pragma unroll
      for (int r = 0; r < 4; ++r) {
        int row = rbase + r;
        if (row < M) {
          float v = acc[mi][ni][r] + bj;
          if constexpr (RELU) v = fmaxf(v, 0.0f);
          if constexpr (HILO) {
            unsigned short h = f2bf(v);
            oh[(long)row * N + col] = h;
            ol[(long)row * N + col] = f2bf(v - bf2f(h));
          } else {
            outf[(long)row * N + col] = v;
          }
        }
      }
    }
  }
}

extern "C" void kernel_launch(void* const* d_in, const int* in_sizes, int n_in,
                              void* d_out, int out_size, void* d_ws, size_t ws_size,
                              hipStream_t stream) {
  const float* x    = (const float*)d_in[0];
  const int*   ei   = (const int*)d_in[1];
  const float* eps1 = (const float*)d_in[2];
  const float* W1a  = (const float*)d_in[3];
  const float* b1a  = (const float*)d_in[4];
  const float* W1b  = (const float*)d_in[5];
  const float* b1b  = (const float*)d_in[6];
  const float* eps2 = (const float*)d_in[7];
  const float* W2a  = (const float*)d_in[8];
  const float* b2a  = (const float*)d_in[9];
  const float* W2b  = (const float*)d_in[10];
  const float* b2b  = (const float*)d_in[11];
  float* out = (float*)d_out;

  const int* srcp = ei;
  const int* dstp = ei + N_EDGES;

  // ---- workspace: two 102.4MB halves, cycled (R6 layout) ----
  char* ws = (char*)d_ws;
  const size_t SZ = (size_t)N_NODES * 256 * sizeof(float);  // 102.4 MB
  char* P1 = ws;
  char* P2 = ws + SZ;

  unsigned short* C1h = (unsigned short*)P1;
  unsigned short* C1l = C1h + (size_t)N_NODES * 128;
  unsigned short* xh  = C1l + (size_t)N_NODES * 128;
  unsigned short* T1h = (unsigned short*)P2;
  unsigned short* T1l = T1h + (size_t)N_NODES * 256;
  unsigned short* Hh = (unsigned short*)P1;
  unsigned short* Hl = Hh + (size_t)N_NODES * 256;
  unsigned short* C2h = (unsigned short*)P2;
  unsigned short* C2l = C2h + (size_t)N_NODES * 256;
  unsigned short* T2h = (unsigned short*)P1;
  unsigned short* T2l = T2h + (size_t)N_NODES * 256;
  unsigned short* W2bh = (unsigned short*)P2;
  unsigned short* W2bl = W2bh + 128 * 256;

  // ---- d_out scratch (all dead before final GEMM overwrites d_out) ----
  char* ob = (char*)d_out;
  int* rowEnd    = (int*)(ob + 400 * 1024);
  int* sortedSrc = (int*)(ob + 800 * 1024);
  size_t wofs = 7340032;
  unsigned short* W1ah = (unsigned short*)(ob + wofs);
  unsigned short* W1al = W1ah + 256 * 128;
  unsigned short* W1bh = (unsigned short*)(ob + wofs + 2 * 65536);
  unsigned short* W1bl = W1bh + 256 * 256;
  unsigned short* W2ah = (unsigned short*)(ob + wofs + 2 * 65536 + 2 * 131072);
  unsigned short* W2al = W2ah + 256 * 256;
  unsigned int* packed = (unsigned int*)(ob + 16 * 1024 * 1024);   // 6.4MB
  int* bucketStart = (int*)(ob + 28 * 1024 * 1024);                // NB+1 ints
  int* bucketTot   = (int*)(ob + 28 * 1024 * 1024 + 8192);         // NB ints
  int* blockHist   = (int*)(ob + 30 * 1024 * 1024);                // NB*SC_BLK

  dim3 blk(256);
  dim3 gAgg((N_NODES + 3) / 4);
  dim3 gW1((128 * 256 + 255) / 256);
  dim3 gW2((256 * 256 + 255) / 256);
  dim3 gXp((N_NODES * 128 + 255) / 256);
  dim3 gGemm((N_NODES + 127) / 128);  // 782, full-N blocks

  // ---- CSR build (no global atomics) + weight/x prep ----
  histA_k<<<dim3(SC_BLK), blk, 0, stream>>>(dstp, blockHist, N_EDGES);
  scanW_k<<<dim3((NB + 3) / 4), blk, 0, stream>>>(blockHist, bucketTot);
  scanB2_k<<<1, dim3(1024), 0, stream>>>(bucketTot, bucketStart);
  scatter2_k<<<dim3(SC_BLK), blk, 0, stream>>>(srcp, dstp, bucketStart,
                                               blockHist, packed, N_EDGES);
  fillB_k<<<dim3(NB), blk, 0, stream>>>(bucketStart, packed, rowEnd, sortedSrc,
                                        N_NODES);
  xprep_k<<<gXp, blk, 0, stream>>>(x, xh, N_NODES * 128);
  wprep_k<<<gW1, blk, 0, stream>>>(W1a, W1ah, W1al, 128, 256);
  wprep_k<<<gW2, blk, 0, stream>>>(W1b, W1bh, W1bl, 256, 256);
  wprep_k<<<gW2, blk, 0, stream>>>(W2a, W2ah, W2al, 256, 256);

  // ---- Layer 1 ----
  agg_s_k<true><<<gAgg, blk, 0, stream>>>(
      xh, x, nullptr, nullptr, eps1, rowEnd, sortedSrc, C1h, C1l, N_NODES, 128, 0);
  gemmW_k<8, true, true><<<gGemm, blk, 0, stream>>>(
      C1h, C1l, W1ah, W1al, b1a, nullptr, T1h, T1l, N_NODES, 128);
  gemmW_k<8, true, true><<<gGemm, blk, 0, stream>>>(
      T1h, T1l, W1bh, W1bl, b1b, nullptr, Hh, Hl, N_NODES, 256);

  // ---- Layer 2 ----
  agg_s_k<false><<<gAgg, blk, 0, stream>>>(
      Hh, nullptr, Hh, Hl, eps2, rowEnd, sortedSrc, C2h, C2l, N_NODES, 256, 0);
  agg_s_k<false><<<gAgg, blk, 0, stream>>>(
      Hh, nullptr, Hh, Hl, eps2, rowEnd, sortedSrc, C2h, C2l, N_NODES, 256, 128);
  gemmW_k<8, true, true><<<gGemm, blk, 0, stream>>>(
      C2h, C2l, W2ah, W2al, b2a, nullptr, T2h, T2l, N_NODES, 256);
  wprep_k<<<gW1, blk, 0, stream>>>(W2b, W2bh, W2bl, 256, 128);  // C2 dead now
  gemmW_k<4, false, false><<<gGemm, blk, 0, stream>>>(
      T2h, T2l, W2bh, W2bl, b2b, out, nullptr, nullptr, N_NODES, 256);
}

// Round 10
// 612.605 us; speedup vs baseline: 1.4129x; 1.3607x over previous
//
#include <hip/hip_runtime.h>

#define N_NODES 100000
#define N_EDGES 1600000
#define NB 782       // ceil(N_NODES/128) buckets of 128 dst nodes
#define SC_BLK 256   // blocks in the binning passes (blockHist is [NB][SC_BLK])

typedef __attribute__((ext_vector_type(8))) short short8;
typedef __attribute__((ext_vector_type(4))) float float4e;

// async 16B global->LDS copy (lane-contiguous LDS dest)
#define GLDS16(g, l)                                                   \
  __builtin_amdgcn_global_load_lds(                                    \
      (const __attribute__((address_space(1))) unsigned int*)(g),      \
      (__attribute__((address_space(3))) unsigned int*)(l), 16, 0, 0)

// ---------------------------------------------------------------------------
// bf16 split helpers (RNE)
// ---------------------------------------------------------------------------
__device__ __forceinline__ unsigned short f2bf(float f) {
  unsigned u = __float_as_uint(f);
  u += 0x7FFFu + ((u >> 16) & 1u);
  return (unsigned short)(u >> 16);
}
__device__ __forceinline__ float bf2f(unsigned short h) {
  return __uint_as_float(((unsigned)h) << 16);
}

// ===========================================================================
// CSR build, zero global atomics (scratch in d_out, dead before final GEMM).
// ===========================================================================
__global__ __launch_bounds__(256) void histA_k(const int* __restrict__ dst,
                                               int* __restrict__ bh, int nE) {
  __shared__ int h[NB];
  const int blk = blockIdx.x, tid = threadIdx.x;
  for (int b = tid; b < NB; b += 256) h[b] = 0;
  __syncthreads();
  const int epb = (nE + SC_BLK - 1) / SC_BLK;
  const int i1 = min(blk * epb + epb, nE);
  for (int i = blk * epb + tid; i < i1; i += 256)
    atomicAdd(&h[dst[i] >> 7], 1);
  __syncthreads();
  for (int b = tid; b < NB; b += 256) bh[b * SC_BLK + blk] = h[b];
}

// one wave per bucket: exclusive scan of 256 block counts (4/lane + shfl_up)
__global__ __launch_bounds__(256) void scanW_k(int* __restrict__ bh,
                                               int* __restrict__ tot) {
  const int b = blockIdx.x * 4 + (threadIdx.x >> 6);
  const int lane = threadIdx.x & 63;
  if (b >= NB) return;
  const int base = b * SC_BLK + lane * 4;
  int v[4];
#pragma unroll
  for (int j = 0; j < 4; ++j) v[j] = bh[base + j];
  int ls = v[0] + v[1] + v[2] + v[3];
  int x = ls;
  for (int off = 1; off < 64; off <<= 1) {
    int y = __shfl_up(x, off);
    if (lane >= off) x += y;
  }
  int run = x - ls;
#pragma unroll
  for (int j = 0; j < 4; ++j) {
    int t = v[j];
    bh[base + j] = run;
    run += t;
  }
  if (lane == 63) tot[b] = run;
}

__global__ __launch_bounds__(1024) void scanB2_k(const int* __restrict__ tot,
                                                 int* __restrict__ bucketStart) {
  __shared__ int sm[1024];
  const int tid = threadIdx.x;
  int v = (tid < NB) ? tot[tid] : 0;
  sm[tid] = v;
  __syncthreads();
  for (int off = 1; off < 1024; off <<= 1) {
    int t = (tid >= off) ? sm[tid - off] : 0;
    __syncthreads();
    sm[tid] += t;
    __syncthreads();
  }
  if (tid < NB) bucketStart[tid] = sm[tid] - v;
  if (tid == NB - 1) bucketStart[NB] = sm[tid];
}

__global__ __launch_bounds__(256) void scatter2_k(
    const int* __restrict__ src, const int* __restrict__ dst,
    const int* __restrict__ bucketStart, const int* __restrict__ bh,
    unsigned int* __restrict__ packed, int nE) {
  __shared__ int cur[NB];
  const int blk = blockIdx.x, tid = threadIdx.x;
  for (int b = tid; b < NB; b += 256)
    cur[b] = bucketStart[b] + bh[b * SC_BLK + blk];
  __syncthreads();
  const int epb = (nE + SC_BLK - 1) / SC_BLK;
  const int i1 = min(blk * epb + epb, nE);
  for (int i = blk * epb + tid; i < i1; i += 256) {
    int d = dst[i];
    int s = src[i];
    int p = atomicAdd(&cur[d >> 7], 1);  // LDS atomic only
    packed[p] = ((unsigned)s << 7) | (unsigned)(d & 127);
  }
}

// one block per bucket: LDS node-count + local scan -> rowEnd; LDS-cursor
// scatter of sortedSrc confined to this bucket's contiguous CSR range.
__global__ __launch_bounds__(256) void fillB_k(
    const int* __restrict__ bucketStart, const unsigned int* __restrict__ packed,
    int* __restrict__ rowEnd, int* __restrict__ sortedSrc, int nNodes) {
  __shared__ int cnt[128];
  __shared__ int cur[128];
  const int b = blockIdx.x;
  const int tid = threadIdx.x;
  const int s0 = bucketStart[b];
  const int ne = bucketStart[b + 1] - s0;
  if (tid < 128) cnt[tid] = 0;
  __syncthreads();
  for (int i = tid; i < ne; i += 256)
    atomicAdd(&cnt[packed[s0 + i] & 127u], 1);
  __syncthreads();
  int v = (tid < 128) ? cnt[tid] : 0;
  for (int off = 1; off < 128; off <<= 1) {
    int t = (tid < 128 && tid >= off) ? cnt[tid - off] : 0;
    __syncthreads();
    if (tid < 128) cnt[tid] += t;
    __syncthreads();
  }
  if (tid < 128) {
    cur[tid] = s0 + cnt[tid] - v;
    int node = b * 128 + tid;
    if (node < nNodes) rowEnd[node] = s0 + cnt[tid];
  }
  __syncthreads();
  for (int i = tid; i < ne; i += 256) {
    unsigned p = packed[s0 + i];
    int idx = atomicAdd(&cur[p & 127u], 1);
    sortedSrc[idx] = (int)(p >> 7);
  }
}

// ===========================================================================
// Weight prep: W[K][N] fp32 -> transposed bf16 hi/lo planes [N][K].
// ===========================================================================
__global__ __launch_bounds__(256) void wprep_k(
    const float* __restrict__ W, unsigned short* __restrict__ th,
    unsigned short* __restrict__ tl, int K, int N) {
  int i = blockIdx.x * blockDim.x + threadIdx.x;
  if (i < K * N) {
    int k = i / N, n = i % N;
    float v = W[i];
    unsigned short h = f2bf(v);
    unsigned short l = f2bf(v - bf2f(h));
    th[(long)n * K + k] = h;
    tl[(long)n * K + k] = l;
  }
}

// x fp32 -> bf16 hi plane (for the gather path)
__global__ __launch_bounds__(256) void xprep_k(const float* __restrict__ x,
                                               unsigned short* __restrict__ xh,
                                               int n) {
  int i = blockIdx.x * blockDim.x + threadIdx.x;
  if (i < n) xh[i] = f2bf(x[i]);
}

// ===========================================================================
// CSR gather-sum (bf16 rows) + GIN combine -> bf16 hi/lo planes.
//   Processes a 128-channel slice [off, off+128) of rows with stride S.
// One wave per node; lane holds 2 channels; 8-deep gather window.
// ===========================================================================
template <bool XF32>
__global__ __launch_bounds__(256) void agg_s_k(
    const unsigned short* __restrict__ feat_h, const float* __restrict__ xf,
    const unsigned short* __restrict__ xh, const unsigned short* __restrict__ xl,
    const float* __restrict__ epsp, const int* __restrict__ rowEnd,
    const int* __restrict__ sortedSrc, unsigned short* __restrict__ oh,
    unsigned short* __restrict__ ol, int M, int S, int off) {
  constexpr int V = 2;
  const int lane = threadIdx.x & 63;
  const int w = (int)((blockIdx.x * blockDim.x + threadIdx.x) >> 6);
  if (w >= M) return;
  const int start = w ? rowEnd[w - 1] : 0;
  const int end = rowEnd[w];
  const int c0 = lane * V + off;

  float acc[V] = {};
  int e = start;
  for (; e + 8 <= end; e += 8) {
    int si[8];
#pragma unroll
    for (int q = 0; q < 8; ++q) si[q] = sortedSrc[e + q];
    ushort2 t[8];
#pragma unroll
    for (int q = 0; q < 8; ++q)
      t[q] = *(const ushort2*)(feat_h + (long)si[q] * S + c0);
#pragma unroll
    for (int q = 0; q < 8; ++q) {
      acc[0] += bf2f(t[q].x);
      acc[1] += bf2f(t[q].y);
    }
  }
  for (; e + 4 <= end; e += 4) {
    int s0 = sortedSrc[e + 0];
    int s1 = sortedSrc[e + 1];
    int s2 = sortedSrc[e + 2];
    int s3 = sortedSrc[e + 3];
    ushort2 a = *(const ushort2*)(feat_h + (long)s0 * S + c0);
    ushort2 b = *(const ushort2*)(feat_h + (long)s1 * S + c0);
    ushort2 c = *(const ushort2*)(feat_h + (long)s2 * S + c0);
    ushort2 d = *(const ushort2*)(feat_h + (long)s3 * S + c0);
    acc[0] += bf2f(a.x) + bf2f(b.x) + bf2f(c.x) + bf2f(d.x);
    acc[1] += bf2f(a.y) + bf2f(b.y) + bf2f(c.y) + bf2f(d.y);
  }
  for (; e < end; ++e) {
    ushort2 a = *(const ushort2*)(feat_h + (long)sortedSrc[e] * S + c0);
    acc[0] += bf2f(a.x);
    acc[1] += bf2f(a.y);
  }

  const float s = 1.0f + epsp[0];
  float xv[V];
  if constexpr (XF32) {
#pragma unroll
    for (int v = 0; v < V; ++v) xv[v] = xf[(long)w * S + c0 + v];
  } else {
#pragma unroll
    for (int v = 0; v < V; ++v)
      xv[v] = bf2f(xh[(long)w * S + c0 + v]) + bf2f(xl[(long)w * S + c0 + v]);
  }

  unsigned short hv[V], lv[V];
#pragma unroll
  for (int v = 0; v < V; ++v) {
    float res = fmaf(s, xv[v], acc[v]);
    hv[v] = f2bf(res);
    lv[v] = f2bf(res - bf2f(hv[v]));
  }
  *(ushort2*)&oh[(long)w * S + c0] = make_ushort2(hv[0], hv[1]);
  *(ushort2*)&ol[(long)w * S + c0] = make_ushort2(lv[0], lv[1]);
}

// ===========================================================================
// Split-bf16 MFMA GEMM, R6-proven structure: 128x128 tile, 4 waves (2x2),
// wave = 64x64 = acc[4][4]; A+B staged per BK=32 via XOR-swizzled
// global_load_lds (32KB single-buffered, zero bank conflicts); plain
// __syncthreads (counted-vmcnt dbuf and B-from-L2 both measured slower,
// R7/R9). NEW vs R6:
//  (1) XCD-bijective block swizzle (m204): 1D grid; consecutive swizzled ids
//      = (m-tile, y) pairs -> A row-panel reuse in per-XCD L2.
//  (2) HILO epilogue bounces acc through the 32KB LDS (swizzle
//      ^((row>>2)&3)<<5, conflict-free) -> 16B coalesced global stores,
//      kills the 27% write amplification of 2B scattered stores.
// ===========================================================================
__device__ __forceinline__ short8 lds_rd(const unsigned short* base, int r,
                                         int q) {
  int L = r * 64 + q * 16;
  int P = L ^ (((L >> 7) & 7) << 4);
  return *(const short8*)((const char*)base + P);
}

#define MFMA_BF16 __builtin_amdgcn_mfma_f32_16x16x32_bf16

template <int NY, bool RELU, bool HILO>
__global__ __launch_bounds__(256, 2) void gemm128_k(
    const unsigned short* __restrict__ Ah, const unsigned short* __restrict__ Al,
    const unsigned short* __restrict__ Bth, const unsigned short* __restrict__ Btl,
    const float* __restrict__ bias, float* __restrict__ outf,
    unsigned short* __restrict__ oh, unsigned short* __restrict__ ol,
    int M, int K, int NOUT) {
  __shared__ unsigned short Sm[16384];  // 32 KB: 4 x 8KB planes, then bounce
  unsigned short* Ash = Sm;
  unsigned short* Asl = Sm + 4096;
  unsigned short* Bsh = Sm + 8192;
  unsigned short* Bsl = Sm + 12288;

  const int tid = threadIdx.x;
  const int lane = tid & 63;
  const int wave = tid >> 6;
  const int l15 = lane & 15;
  const int quad = lane >> 4;
  const int wm = wave >> 1;
  const int wn = wave & 1;

  // XCD-bijective swizzle (m204): orig id -> contiguous chunk per XCD
  const int nwg = gridDim.x;
  const int q8 = nwg >> 3, r8 = nwg & 7;
  const int xcd = blockIdx.x & 7, idx = blockIdx.x >> 3;
  const int lin =
      (xcd < r8 ? xcd * (q8 + 1) : r8 * (q8 + 1) + (xcd - r8) * q8) + idx;
  int bx, n0;
  if (NY == 2) {
    bx = lin >> 1;            // consecutive pair shares A row-panel
    n0 = (lin & 1) * 128;
  } else {
    bx = lin;
    n0 = 0;
  }
  const int m0 = bx * 128;

  float4e acc[4][4];
#pragma unroll
  for (int i = 0; i < 4; ++i)
#pragma unroll
    for (int j = 0; j < 4; ++j) acc[i][j] = 0.0f;

  for (int k0 = 0; k0 < K; k0 += 32) {
#pragma unroll
    for (int h = 0; h < 2; ++h) {
      int c = h * 256 + tid;                  // physical 16B chunk
      int P = c * 16;
      int L = P ^ (((P >> 7) & 7) << 4);      // involutive swizzle
      int r = L >> 6;
      int q = (L >> 4) & 3;
      int ra = min(m0 + r, M - 1);            // clamp: masked rows only
      long ga = (long)ra * K + k0 + q * 8;
      GLDS16(Ah + ga, &Ash[c * 8]);
      GLDS16(Al + ga, &Asl[c * 8]);
      long gb = (long)(n0 + r) * K + k0 + q * 8;
      GLDS16(Bth + gb, &Bsh[c * 8]);
      GLDS16(Btl + gb, &Bsl[c * 8]);
    }
    __syncthreads();

    short8 ah[4], al[4];
#pragma unroll
    for (int mi = 0; mi < 4; ++mi) {
      ah[mi] = lds_rd(Ash, wm * 64 + mi * 16 + l15, quad);
      al[mi] = lds_rd(Asl, wm * 64 + mi * 16 + l15, quad);
    }
#pragma unroll
    for (int ni = 0; ni < 4; ++ni) {
      short8 bh = lds_rd(Bsh, wn * 64 + ni * 16 + l15, quad);
      short8 bl = lds_rd(Bsl, wn * 64 + ni * 16 + l15, quad);
#pragma unroll
      for (int mi = 0; mi < 4; ++mi) {
        acc[mi][ni] = MFMA_BF16(ah[mi], bh, acc[mi][ni], 0, 0, 0);
        acc[mi][ni] = MFMA_BF16(ah[mi], bl, acc[mi][ni], 0, 0, 0);
        acc[mi][ni] = MFMA_BF16(al[mi], bh, acc[mi][ni], 0, 0, 0);
      }
    }
    __syncthreads();
  }

  if constexpr (HILO) {
    // ---- plane bounce: acc -> swizzled LDS [128][128] -> 16B stores ----
#pragma unroll
    for (int pass = 0; pass < 2; ++pass) {
#pragma unroll
      for (int ni = 0; ni < 4; ++ni) {
        int col = wn * 64 + ni * 16 + l15;
        float bj = bias[n0 + col];
#pragma unroll
        for (int mi = 0; mi < 4; ++mi) {
#pragma unroll
          for (int r = 0; r < 4; ++r) {
            int row = wm * 64 + mi * 16 + quad * 4 + r;
            float v = acc[mi][ni][r] + bj;
            if constexpr (RELU) v = fmaxf(v, 0.0f);
            unsigned short hv = f2bf(v);
            unsigned short wv = pass ? f2bf(v - bf2f(hv)) : hv;
            int B = row * 256 + col * 2;
            int SB = B ^ (((row >> 2) & 3) << 5);
            *(unsigned short*)((char*)Sm + SB) = wv;
          }
        }
      }
      __syncthreads();
      unsigned short* dst = pass ? ol : oh;
#pragma unroll
      for (int i = 0; i < 8; ++i) {
        int li = i * 256 + tid;
        int row = li >> 4, chk = li & 15;
        int B = row * 256 + chk * 16;
        int SB = B ^ (((row >> 2) & 3) << 5);
        if (m0 + row < M)
          *(short8*)&dst[(long)(m0 + row) * NOUT + n0 + chk * 8] =
              *(const short8*)((const char*)Sm + SB);
      }
      __syncthreads();
    }
  } else {
#pragma unroll
    for (int ni = 0; ni < 4; ++ni) {
      int col = n0 + wn * 64 + ni * 16 + l15;
      float bj = bias[col];
#pragma unroll
      for (int mi = 0; mi < 4; ++mi) {
        int rbase = m0 + wm * 64 + mi * 16 + quad * 4;
#pragma unroll
        for (int r = 0; r < 4; ++r) {
          int row = rbase + r;
          if (row < M) {
            float v = acc[mi][ni][r] + bj;
            if constexpr (RELU) v = fmaxf(v, 0.0f);
            outf[(long)row * NOUT + col] = v;
          }
        }
      }
    }
  }
}

extern "C" void kernel_launch(void* const* d_in, const int* in_sizes, int n_in,
                              void* d_out, int out_size, void* d_ws, size_t ws_size,
                              hipStream_t stream) {
  const float* x    = (const float*)d_in[0];
  const int*   ei   = (const int*)d_in[1];
  const float* eps1 = (const float*)d_in[2];
  const float* W1a  = (const float*)d_in[3];
  const float* b1a  = (const float*)d_in[4];
  const float* W1b  = (const float*)d_in[5];
  const float* b1b  = (const float*)d_in[6];
  const float* eps2 = (const float*)d_in[7];
  const float* W2a  = (const float*)d_in[8];
  const float* b2a  = (const float*)d_in[9];
  const float* W2b  = (const float*)d_in[10];
  const float* b2b  = (const float*)d_in[11];
  float* out = (float*)d_out;

  const int* srcp = ei;
  const int* dstp = ei + N_EDGES;

  // ---- workspace: two 102.4MB halves, cycled (R6 layout) ----
  char* ws = (char*)d_ws;
  const size_t SZ = (size_t)N_NODES * 256 * sizeof(float);  // 102.4 MB
  char* P1 = ws;
  char* P2 = ws + SZ;

  unsigned short* C1h = (unsigned short*)P1;
  unsigned short* C1l = C1h + (size_t)N_NODES * 128;
  unsigned short* xh  = C1l + (size_t)N_NODES * 128;
  unsigned short* T1h = (unsigned short*)P2;
  unsigned short* T1l = T1h + (size_t)N_NODES * 256;
  unsigned short* Hh = (unsigned short*)P1;
  unsigned short* Hl = Hh + (size_t)N_NODES * 256;
  unsigned short* C2h = (unsigned short*)P2;
  unsigned short* C2l = C2h + (size_t)N_NODES * 256;
  unsigned short* T2h = (unsigned short*)P1;
  unsigned short* T2l = T2h + (size_t)N_NODES * 256;
  unsigned short* W2bh = (unsigned short*)P2;
  unsigned short* W2bl = W2bh + 128 * 256;

  // ---- d_out scratch (all dead before final GEMM overwrites d_out) ----
  char* ob = (char*)d_out;
  int* rowEnd    = (int*)(ob + 400 * 1024);
  int* sortedSrc = (int*)(ob + 800 * 1024);
  size_t wofs = 7340032;
  unsigned short* W1ah = (unsigned short*)(ob + wofs);
  unsigned short* W1al = W1ah + 256 * 128;
  unsigned short* W1bh = (unsigned short*)(ob + wofs + 2 * 65536);
  unsigned short* W1bl = W1bh + 256 * 256;
  unsigned short* W2ah = (unsigned short*)(ob + wofs + 2 * 65536 + 2 * 131072);
  unsigned short* W2al = W2ah + 256 * 256;
  unsigned int* packed = (unsigned int*)(ob + 16 * 1024 * 1024);   // 6.4MB
  int* bucketStart = (int*)(ob + 28 * 1024 * 1024);                // NB+1 ints
  int* bucketTot   = (int*)(ob + 28 * 1024 * 1024 + 8192);         // NB ints
  int* blockHist   = (int*)(ob + 30 * 1024 * 1024);                // NB*SC_BLK

  dim3 blk(256);
  dim3 gAgg((N_NODES + 3) / 4);
  dim3 gW1((128 * 256 + 255) / 256);
  dim3 gW2((256 * 256 + 255) / 256);
  dim3 gXp((N_NODES * 128 + 255) / 256);
  dim3 gGemm2(((N_NODES + 127) / 128) * 2);  // 1564, 1D (swizzled in-kernel)
  dim3 gGemm1((N_NODES + 127) / 128);        // 782

  // ---- CSR build (no global atomics) + weight/x prep ----
  histA_k<<<dim3(SC_BLK), blk, 0, stream>>>(dstp, blockHist, N_EDGES);
  scanW_k<<<dim3((NB + 3) / 4), blk, 0, stream>>>(blockHist, bucketTot);
  scanB2_k<<<1, dim3(1024), 0, stream>>>(bucketTot, bucketStart);
  scatter2_k<<<dim3(SC_BLK), blk, 0, stream>>>(srcp, dstp, bucketStart,
                                               blockHist, packed, N_EDGES);
  fillB_k<<<dim3(NB), blk, 0, stream>>>(bucketStart, packed, rowEnd, sortedSrc,
                                        N_NODES);
  xprep_k<<<gXp, blk, 0, stream>>>(x, xh, N_NODES * 128);
  wprep_k<<<gW1, blk, 0, stream>>>(W1a, W1ah, W1al, 128, 256);
  wprep_k<<<gW2, blk, 0, stream>>>(W1b, W1bh, W1bl, 256, 256);
  wprep_k<<<gW2, blk, 0, stream>>>(W2a, W2ah, W2al, 256, 256);

  // ---- Layer 1 ----
  agg_s_k<true><<<gAgg, blk, 0, stream>>>(
      xh, x, nullptr, nullptr, eps1, rowEnd, sortedSrc, C1h, C1l, N_NODES, 128, 0);
  gemm128_k<2, true, true><<<gGemm2, blk, 0, stream>>>(
      C1h, C1l, W1ah, W1al, b1a, nullptr, T1h, T1l, N_NODES, 128, 256);
  gemm128_k<2, true, true><<<gGemm2, blk, 0, stream>>>(
      T1h, T1l, W1bh, W1bl, b1b, nullptr, Hh, Hl, N_NODES, 256, 256);

  // ---- Layer 2 ----
  agg_s_k<false><<<gAgg, blk, 0, stream>>>(
      Hh, nullptr, Hh, Hl, eps2, rowEnd, sortedSrc, C2h, C2l, N_NODES, 256, 0);
  agg_s_k<false><<<gAgg, blk, 0, stream>>>(
      Hh, nullptr, Hh, Hl, eps2, rowEnd, sortedSrc, C2h, C2l, N_NODES, 256, 128);
  gemm128_k<2, true, true><<<gGemm2, blk, 0, stream>>>(
      C2h, C2l, W2ah, W2al, b2a, nullptr, T2h, T2l, N_NODES, 256, 256);
  wprep_k<<<gW1, blk, 0, stream>>>(W2b, W2bh, W2bl, 256, 128);  // C2 dead now
  gemm128_k<1, false, false><<<gGemm1, blk, 0, stream>>>(
      T2h, T2l, W2bh, W2bl, b2b, out, nullptr, nullptr, N_NODES, 256, 128);
}